// Round 10
// baseline (214.667 us; speedup 1.0000x reference)
//
#include <hip/hip_runtime.h>
#include <math.h>

#define IND   64
#define OUTD  101
#define RPB   32         // rows per tile (2 row-tiles of 16)
#define NCT   7          // 7 col-tiles x 16 = 112 padded cols

typedef _Float16 half8 __attribute__((ext_vector_type(8)));
typedef float    f32x4 __attribute__((ext_vector_type(4)));

__global__ __launch_bounds__(64, 3) void density_kernel(
    const float* __restrict__ t,
    const float* __restrict__ x,
    const float* __restrict__ weight,
    const float* __restrict__ bias,
    const int*   __restrict__ num_grid,
    float* __restrict__ out1,
    float* __restrict__ out_interp,
    int n_rows, int n_tiles, int n_blocks)
{
    __shared__ alignas(16) int liui[RPB];   // per-row packed (Li | Ui<<16)
    __shared__ float accL[RPB];             // per-row p[Li]
    __shared__ float accU[RPB];             // per-row p[Ui]

    const int lane = threadIdx.x;
    const int lc   = lane & 15;        // col-in-tile (R5 mapping)
    const int lg   = lane >> 4;        // k-group / row-group
    const float ngf = (float)num_grid[0];

    // ---- W fragments + bias: 63 VGPR, loaded ONCE per persistent block ----
    half8 wf[NCT][2];
    float biasv[NCT];
#pragma unroll
    for (int ct = 0; ct < NCT; ++ct) {
        const int col  = ct * 16 + lc;
        const int colc = (col < OUTD) ? col : (OUTD - 1);
        biasv[ct] = (col < OUTD) ? bias[col] : -1e30f;   // pads killed via bias
#pragma unroll
        for (int kg = 0; kg < 2; ++kg) {
            half8 h;
#pragma unroll
            for (int j = 0; j < 8; ++j)
                h[j] = (_Float16)weight[(kg * 32 + lg * 8 + j) * OUTD + colc];
            wf[ct][kg] = h;
        }
    }

    #define XPTR(TILE, RT) \
        ((const f32x4*)(x + (size_t)min((TILE) * RPB + (RT) * 16 + lc, n_rows - 1) * IND + lg * 8))
    #define NTL4(P, D0, D1, D2, D3) \
        { const f32x4* _p = (P); \
          D0 = __builtin_nontemporal_load(_p);     D1 = __builtin_nontemporal_load(_p + 1); \
          D2 = __builtin_nontemporal_load(_p + 8); D3 = __builtin_nontemporal_load(_p + 9); }

    // 2 buffers, 2-deep prefetch: consume (tile,RT), then reload same regs
    // with (tile+n_blocks,RT) -> issue->consume distance = 2 row-tiles.
    f32x4 pa0, pa1, pa2, pa3, pb0, pb1, pb2, pb3;

    int tile = blockIdx.x;
    NTL4(XPTR(tile, 0), pa0, pa1, pa2, pa3)
    NTL4(XPTR(tile, 1), pb0, pb1, pb2, pb3)

    #define PROCESS(RT, C0, C1, C2, C3, PT)                                      \
    {                                                                            \
        half8 a0, a1;                                                            \
        _Pragma("unroll")                                                        \
        for (int i = 0; i < 4; ++i) {                                            \
            a0[i] = (_Float16)C0[i]; a0[4 + i] = (_Float16)C1[i];                \
            a1[i] = (_Float16)C2[i]; a1[4 + i] = (_Float16)C3[i];                \
        }                                                                        \
        NTL4(XPTR(PT, RT), C0, C1, C2, C3)   /* prefetch 2 rt ahead */           \
        f32x4 c[NCT];                                                            \
        _Pragma("unroll")                                                        \
        for (int ct = 0; ct < NCT; ++ct) {                                       \
            f32x4 ci = {biasv[ct], biasv[ct], biasv[ct], biasv[ct]};             \
            ci = __builtin_amdgcn_mfma_f32_16x16x32_f16(a0, wf[ct][0], ci,0,0,0);\
            ci = __builtin_amdgcn_mfma_f32_16x16x32_f16(a1, wf[ct][1], ci,0,0,0);\
            c[ct] = ci;                                                          \
        }                                                                        \
        float m[4], s[4];                                                        \
        _Pragma("unroll")                                                        \
        for (int j = 0; j < 4; ++j) {                                            \
            float mj = c[0][j];                                                  \
            _Pragma("unroll")                                                    \
            for (int ct = 1; ct < NCT; ++ct) mj = fmaxf(mj, c[ct][j]);           \
            _Pragma("unroll")                                                    \
            for (int d = 1; d < 16; d <<= 1) mj = fmaxf(mj, __shfl_xor(mj,d,64));\
            m[j] = mj; s[j] = 0.0f;                                              \
        }                                                                        \
        _Pragma("unroll")                                                        \
        for (int ct = 0; ct < NCT; ++ct)                                         \
            _Pragma("unroll")                                                    \
            for (int j = 0; j < 4; ++j) {                                        \
                const float e = __expf(c[ct][j] - m[j]);                         \
                c[ct][j] = e; s[j] += e;                                         \
            }                                                                    \
        _Pragma("unroll")                                                        \
        for (int j = 0; j < 4; ++j) {                                            \
            _Pragma("unroll")                                                    \
            for (int d = 1; d < 16; d <<= 1) s[j] += __shfl_xor(s[j], d, 64);    \
            float inv = __builtin_amdgcn_rcpf(s[j]);                             \
            inv = inv * (2.0f - s[j] * inv);                                     \
            s[j] = inv;                                                          \
        }                                                                        \
        _Pragma("unroll")                                                        \
        for (int ct = 0; ct < NCT; ++ct)                                         \
            _Pragma("unroll")                                                    \
            for (int j = 0; j < 4; ++j) c[ct][j] *= s[j];                        \
        const int rbase = row0 + RT * 16 + lg * 4;                               \
        _Pragma("unroll")                                                        \
        for (int j = 0; j < 4; ++j) {                                            \
            const int r = rbase + j;                                             \
            if (r < n_rows) {                                                    \
                float* orow = out1 + (size_t)r * OUTD;                           \
                _Pragma("unroll")                                                \
                for (int ct = 0; ct < NCT; ++ct) {                               \
                    const int col = ct * 16 + lc;                                \
                    if (col < OUTD)                                              \
                        __builtin_nontemporal_store(c[ct][j], &orow[col]);       \
                }                                                                \
            }                                                                    \
        }                                                                        \
        const int rl = RT * 16 + lg * 4;                                         \
        int lup[4];                                                              \
        *(int4*)lup = *(const int4*)&liui[rl];                                   \
        _Pragma("unroll")                                                        \
        for (int j = 0; j < 4; ++j) {                                            \
            const int LiR = lup[j] & 0xffff;                                     \
            const int UiR = lup[j] >> 16;                                        \
            const int ctL = LiR >> 4, lcL = LiR & 15;                            \
            const int ctU = UiR >> 4, lcU = UiR & 15;                            \
            float pL = 0.0f, pU = 0.0f;                                          \
            _Pragma("unroll")                                                    \
            for (int ct = 0; ct < NCT; ++ct) {                                   \
                pL = (ct == ctL) ? c[ct][j] : pL;                                \
                pU = (ct == ctU) ? c[ct][j] : pU;                                \
            }                                                                    \
            if (lc == lcL) accL[rl + j] = pL;                                    \
            if (lc == lcU) accU[rl + j] = pU;                                    \
        }                                                                        \
    }

    for (; tile < n_tiles; tile += n_blocks) {
        const int row0 = tile * RPB;

        // own-row interp indices -> LDS broadcast (rows 0..31 of the tile)
        const int lr  = lane & 31;
        const int gr  = row0 + lr;
        const int grc = (gr < n_rows) ? gr : (n_rows - 1);
        const float tB = t[grc] * ngf;
        const float Uf = ceilf(tB);
        const float inter = 1.0f - (Uf - tB);
        float Lf = Uf - 1.0f;
        if (Lf < 0.0f) Lf += 1.0f;
        if (lane < 32) liui[lane] = ((int)Lf) | (((int)Uf) << 16);
        __syncthreads();

        const int ntile = (tile + n_blocks < n_tiles) ? tile + n_blocks : tile;

        PROCESS(0, pa0, pa1, pa2, pa3, ntile)
        PROCESS(1, pb0, pb1, pb2, pb3, ntile)

        __syncthreads();

        // interp: lane = row (0..31), fp32 lerp
        if (lane < 32 && gr < n_rows) {
            const float Lv = accL[lane];
            const float Uv = accU[lane];
            __builtin_nontemporal_store(Lv + (Uv - Lv) * inter, &out_interp[gr]);
        }
    }
    #undef PROCESS
    #undef NTL4
    #undef XPTR
}

extern "C" void kernel_launch(void* const* d_in, const int* in_sizes, int n_in,
                              void* d_out, int out_size, void* d_ws, size_t ws_size,
                              hipStream_t stream) {
    const float* t  = (const float*)d_in[0];
    const float* x  = (const float*)d_in[1];
    const float* w  = (const float*)d_in[2];
    const float* b  = (const float*)d_in[3];
    const int*   ng = (const int*)d_in[4];
    const int n_rows = in_sizes[0];

    float* out1       = (float*)d_out;
    float* out_interp = out1 + (size_t)n_rows * OUTD;

    const int n_tiles  = (n_rows + RPB - 1) / RPB;   // 31250
    const int n_blocks = 3072;                       // 3 waves/SIMD x 1024 SIMDs
    density_kernel<<<dim3(n_blocks), dim3(64), 0, stream>>>(
        t, x, w, b, ng, out1, out_interp, n_rows, n_tiles, n_blocks);
}